// Round 1
// 193.167 us; speedup vs baseline: 1.0679x; 1.0679x over previous
//
#include <hip/hip_runtime.h>
#include <hip/hip_bf16.h>

typedef __bf16 bf16;
typedef __bf16 bf16x4 __attribute__((ext_vector_type(4)));
typedef __bf16 bf16x8 __attribute__((ext_vector_type(8)));
typedef float f32x4 __attribute__((ext_vector_type(4)));

typedef __attribute__((address_space(3))) void lds_void;
typedef const __attribute__((address_space(1))) void gbl_void;

#define D_MODEL 1024
#define NHEAD 16
#define DEPTH 64
#define SEQ 2048
#define BATCH 2
#define NTOK (BATCH * SEQ)   // 4096

// 1/sqrt(64) * log2(e): folded into q so attention exp is a bare exp2.
#define Q_SCALE 0.18033688f

// ---------------------------------------------------------------------------
// Kernel 1: prep = weight transpose+convert (z=0..3) + x convert (z=4..7).
// ---------------------------------------------------------------------------
__global__ __launch_bounds__(256) void prep(const float* __restrict__ w0,
                                            const float* __restrict__ w1,
                                            const float* __restrict__ w2,
                                            const float* __restrict__ w3,
                                            const float* __restrict__ x,
                                            bf16* __restrict__ wtb,
                                            bf16* __restrict__ xb) {
    int z = blockIdx.z;
    int tx = threadIdx.x, ty = threadIdx.y;   // (32, 8)
    if (z < 4) {
        const float* w = (z == 0) ? w0 : (z == 1) ? w1 : (z == 2) ? w2 : w3;
        bf16* d = wtb + (size_t)z * D_MODEL * D_MODEL;
        __shared__ float tile[32][33];
        int c0 = blockIdx.x * 32;   // source col block (n)
        int r0 = blockIdx.y * 32;   // source row block (k)
#pragma unroll
        for (int i = 0; i < 4; i++)
            tile[ty + i * 8][tx] = w[(size_t)(r0 + ty + i * 8) * D_MODEL + c0 + tx];
        __syncthreads();
#pragma unroll
        for (int i = 0; i < 4; i++)
            d[(size_t)(c0 + ty + i * 8) * D_MODEL + r0 + tx] = (bf16)tile[tx][ty + i * 8];
    } else {
        int t = ty * 32 + tx;
        size_t i = ((size_t)(z - 4) * 1024 + blockIdx.y * 32 + blockIdx.x) * 256 + t;
        float4 v = ((const float4*)x)[i];
        bf16x4 o = {(bf16)v.x, (bf16)v.y, (bf16)v.z, (bf16)v.w};
        *(bf16x4*)&xb[i * 4] = o;
    }
}

// ---------------------------------------------------------------------------
// Kernel 2: QKV projection as ONE fused GEMM: M=4096 tokens x N=3072 (q|k|v
// features) x K=1024.  256x256 tile, BK=64, 8 waves (2Mx4N), 8-phase
// schedule with counted vmcnt(6) (T2+T3+T4+T5 per the 256-sq template).
//
// LDS (128 KiB): A[2 buf][2 kq][256 rows][32 K] bf16 (32KB/buf) at 0,
//                B same layout at +32768 elems.  Half-tile = one (op,kq)
//                slab of 16KB = 512 thr x 2 x 16B global_load_lds.
// Swizzle: 16B chunk c of row r stored at c ^ ((r>>1)&3).  Write side is
// linear (global_load_lds) so the SOURCE chunk is pre-swizzled; read side
// applies the same XOR -> every 8 consecutive lanes of a ds_read_b128 hit
// 8 distinct 16B bank slots (2-way max over the wave = free).
//
// Stage schedule per K-tile U (phases q0..q3 consume (k0,m0),(k0,m1),
// (k1,m0),(k1,m1)):  q0 stages A-k1(U+1), q1 B-k0(U+2), q2 A-k0(U+2),
// q3 B-k1(U+2)+vmcnt(6).  Each staged region's last reader drained at the
// previous phase's trailing barrier; vmcnt(6) at q3 leaves exactly the 3
// newest halves in flight => next K-tile fully landed.  Tail stages wrap
// (&15) to keep vmcnt counts exact (data never consumed).
// ---------------------------------------------------------------------------
__global__ __launch_bounds__(512, 2) void qkv_gemm(const bf16* __restrict__ xb,
                                                   const bf16* __restrict__ wtb,
                                                   const float* __restrict__ bq,
                                                   const float* __restrict__ bk,
                                                   const float* __restrict__ bv,
                                                   bf16* __restrict__ q,
                                                   bf16* __restrict__ k,
                                                   bf16* __restrict__ v) {
    __shared__ bf16 sm[65536];   // 128 KiB

    // bijective XCD swizzle: 192 blocks = 8 XCDs x 24
    const int flat = blockIdx.x;
    const int wg = (flat & 7) * 24 + (flat >> 3);
    const int mt = wg & 15, nt = wg >> 4;     // wg = nt*16 + mt
    const int row0 = mt << 8;                 // token base
    const int z = nt >> 2;                    // 0=q 1=k 2=v
    const int nb = (nt & 3) << 8;             // feature base within z

    const int tid = threadIdx.x;
    const int lane = tid & 63, wave = tid >> 6;
    const int wm = wave >> 2, wn = wave & 3;  // 2 x 4 wave grid
    const int quad = lane >> 4, l16 = lane & 15;
    const int kch = ((quad ^ ((l16 >> 1) & 3)) << 3);   // swizzled 16B chunk (elems)

    // staging geometry: thread -> (row = wave*32 + i*16 + srow, chunk = lane&3)
    const int srow = lane >> 2;
    const int scg = (lane & 3) ^ ((lane >> 3) & 3);     // pre-swizzled src chunk
    const int stDst = wave * 1024 + lane * 8;           // elems within half

    const bf16* Ag = xb + (size_t)(row0 + wave * 32 + srow) * D_MODEL + scg * 8;
    const bf16* Bg = wtb + (size_t)z * D_MODEL * D_MODEL
                   + (size_t)(nb + wave * 32 + srow) * D_MODEL + scg * 8;

    f32x4 acc[8][4] = {};
    bf16x8 bfr[4];

#define GLL(SRC, DST) __builtin_amdgcn_global_load_lds((gbl_void*)(SRC), (lds_void*)(DST), 16, 0, 0)
#define STG_A(T_, KQ_, BUF_) { \
    const bf16* s_ = Ag + (T_) * 64 + (KQ_) * 32; \
    bf16* d_ = sm + (BUF_) * 16384 + (KQ_) * 8192 + stDst; \
    GLL(s_, d_); GLL(s_ + 16 * D_MODEL, d_ + 512); }
#define STG_B(T_, KQ_, BUF_) { \
    const bf16* s_ = Bg + (T_) * 64 + (KQ_) * 32; \
    bf16* d_ = sm + 32768 + (BUF_) * 16384 + (KQ_) * 8192 + stDst; \
    GLL(s_, d_); GLL(s_ + 16 * D_MODEL, d_ + 512); }
#define WAIT6 { asm volatile("s_waitcnt vmcnt(6)" ::: "memory"); }
#define NOW

#define PHASE(BUF_, KQ_, MQ_, STG_STMT, WAIT_STMT) { \
    bf16x8 af[4]; \
    const int ab_ = (BUF_) * 16384 + (KQ_) * 8192 + (wm * 128 + (MQ_) * 64 + l16) * 32 + kch; \
    _Pragma("unroll") \
    for (int i_ = 0; i_ < 4; i_++) af[i_] = *(const bf16x8*)&sm[ab_ + i_ * 512]; \
    if ((MQ_) == 0) { \
        const int bb_ = 32768 + (BUF_) * 16384 + (KQ_) * 8192 + (wn * 64 + l16) * 32 + kch; \
        _Pragma("unroll") \
        for (int j_ = 0; j_ < 4; j_++) bfr[j_] = *(const bf16x8*)&sm[bb_ + j_ * 512]; \
    } \
    STG_STMT; \
    WAIT_STMT; \
    __builtin_amdgcn_sched_barrier(0); \
    __builtin_amdgcn_s_barrier(); \
    __builtin_amdgcn_s_setprio(1); \
    _Pragma("unroll") \
    for (int i_ = 0; i_ < 4; i_++) \
        _Pragma("unroll") \
        for (int j_ = 0; j_ < 4; j_++) \
            acc[(MQ_) * 4 + i_][j_] = __builtin_amdgcn_mfma_f32_16x16x32_bf16( \
                af[i_], bfr[j_], acc[(MQ_) * 4 + i_][j_], 0, 0, 0); \
    __builtin_amdgcn_s_setprio(0); \
    __builtin_amdgcn_sched_barrier(0); \
    __builtin_amdgcn_s_barrier(); }

    // prologue: 7 halves in steady-state issue order
    STG_B(0, 0, 0);
    STG_A(0, 0, 0);
    STG_B(0, 1, 0);
    STG_A(0, 1, 0);
    asm volatile("s_waitcnt vmcnt(4)" ::: "memory");
    STG_B(1, 0, 1);
    STG_A(1, 0, 1);
    STG_B(1, 1, 1);
    asm volatile("s_waitcnt vmcnt(6)" ::: "memory");
    __builtin_amdgcn_sched_barrier(0);
    __builtin_amdgcn_s_barrier();

#pragma unroll 1
    for (int it = 0; it < 8; ++it) {
        const int t1 = 2 * it + 1;
        const int t2 = (2 * it + 2) & 15;   // wrap keeps vmcnt counts exact at tail
        const int t3 = (2 * it + 3) & 15;
        PHASE(0, 0, 0, STG_A(t1, 1, 1), NOW)      // ph1
        PHASE(0, 0, 1, STG_B(t2, 0, 0), NOW)      // ph2
        PHASE(0, 1, 0, STG_A(t2, 0, 0), NOW)      // ph3
        PHASE(0, 1, 1, STG_B(t2, 1, 0), WAIT6)    // ph4
        PHASE(1, 0, 0, STG_A(t2, 1, 0), NOW)      // ph5
        PHASE(1, 0, 1, STG_B(t3, 0, 1), NOW)      // ph6
        PHASE(1, 1, 0, STG_A(t3, 0, 1), NOW)      // ph7
        PHASE(1, 1, 1, STG_B(t3, 1, 1), WAIT6)    // ph8
    }

#undef PHASE
#undef WAIT6
#undef NOW
#undef STG_A
#undef STG_B
#undef GLL

    // epilogue: acc[mi][j] row(token)=quad*4+r, col(feature)=l16
    const float* bias = (z == 0) ? bq : (z == 1) ? bk : bv;
    const int bI = row0 >> 11;          // whole block in one batch (256 | 2048)
    const int sBase = row0 & 2047;
    if (z < 2) {
        bf16* dst = (z == 0) ? q : k;   // [B,H,S,64]
        const float scl = (z == 0) ? Q_SCALE : 1.0f;
#pragma unroll
        for (int j = 0; j < 4; j++) {
            const int f = nb + wn * 64 + j * 16 + l16;
            const float bi = bias[f];
            const int hh = f >> 6, d = f & 63;
            bf16* dcol = dst + ((size_t)(bI * NHEAD + hh) * SEQ) * DEPTH + d;
#pragma unroll
            for (int mi = 0; mi < 8; mi++) {
                const int s0 = sBase + wm * 128 + (mi >> 2) * 64 + (mi & 3) * 16 + quad * 4;
#pragma unroll
                for (int r = 0; r < 4; r++)
                    dcol[(size_t)(s0 + r) * DEPTH] = (bf16)((acc[mi][j][r] + bi) * scl);
            }
        }
    } else {
        // v: [B,H,64,S]; each lane's 4 regs are 4 consecutive tokens -> bf16x4
#pragma unroll
        for (int j = 0; j < 4; j++) {
            const int f = nb + wn * 64 + j * 16 + l16;
            const float bi = bias[f];
            const int hh = f >> 6, d = f & 63;
            bf16* vrow = v + ((size_t)(bI * NHEAD + hh) * DEPTH + d) * SEQ;
#pragma unroll
            for (int mi = 0; mi < 8; mi++) {
                const int s0 = sBase + wm * 128 + (mi >> 2) * 64 + (mi & 3) * 16 + quad * 4;
                f32x4 a = acc[mi][j];
                bf16x4 ob = {(bf16)(a[0] + bi), (bf16)(a[1] + bi),
                             (bf16)(a[2] + bi), (bf16)(a[3] + bi)};
                *(bf16x4*)&vrow[s0] = ob;
            }
        }
    }
}

// ---------------------------------------------------------------------------
// Kernel 3: flash attention (unchanged this round).
// ---------------------------------------------------------------------------
__global__ __launch_bounds__(256) void attn(const bf16* __restrict__ q,
                                            const bf16* __restrict__ k,
                                            const bf16* __restrict__ v,
                                            bf16* __restrict__ ctx) {
    __shared__ bf16 Ks[64 * 72];        // [kv][d]  pad 72
    __shared__ bf16 Vs[64 * 72];        // [d][kv]  pad 72
    __shared__ bf16 Ps[4][32 * 72];     // per wave [q local][kv] pad 72
    const int tid = threadIdx.x;
    const int lane = tid & 63, wave = tid >> 6;
    const int quad = lane >> 4, l16 = lane & 15;
    const int bh = blockIdx.x;
    const int q0 = blockIdx.y * 128;
    const size_t hb = (size_t)bh * SEQ * DEPTH;
    const bf16* qh = q + hb;
    const bf16* kh = k + hb;            // [S][64]
    const bf16* vh = v + hb;            // [64][S]

    bf16x8 bq_[2][2];
#pragma unroll
    for (int g = 0; g < 2; g++) {
        int qrow = q0 + wave * 32 + g * 16 + l16;
#pragma unroll
        for (int c = 0; c < 2; c++)
            bq_[g][c] = *(const bf16x8*)&qh[(size_t)qrow * DEPTH + c * 32 + quad * 8];
    }
    bf16* myP = &Ps[wave][0];

    bf16x8 ones;
#pragma unroll
    for (int i = 0; i < 8; i++) ones[i] = (bf16)1.0f;

    f32x4 ov[2][4] = {};
    f32x4 lacc[2] = {};

    const int srow = tid >> 2, scol = (tid & 3) << 4;
    const bf16* kg = kh + (size_t)srow * DEPTH + scol;
    const bf16* vg = vh + (size_t)srow * SEQ + scol;
    bf16* ksd = &Ks[srow * 72 + scol];
    bf16* vsd = &Vs[srow * 72 + scol];

    bf16x8 kr0 = *(const bf16x8*)kg, kr1 = *(const bf16x8*)(kg + 8);
    bf16x8 vr0 = *(const bf16x8*)vg, vr1 = *(const bf16x8*)(vg + 8);

    for (int t0 = 0; t0 < SEQ; t0 += 64) {
        __syncthreads();
        *(bf16x8*)ksd = kr0;  *(bf16x8*)(ksd + 8) = kr1;
        *(bf16x8*)vsd = vr0;  *(bf16x8*)(vsd + 8) = vr1;
        __syncthreads();
        if (t0 + 64 < SEQ) {
            const bf16* kgn = kg + (size_t)(t0 + 64) * DEPTH;
            const bf16* vgn = vg + (t0 + 64);
            kr0 = *(const bf16x8*)kgn;  kr1 = *(const bf16x8*)(kgn + 8);
            vr0 = *(const bf16x8*)vgn;  vr1 = *(const bf16x8*)(vgn + 8);
        }
        f32x4 sc[2][4] = {};
#pragma unroll
        for (int c = 0; c < 2; c++)
#pragma unroll
            for (int j = 0; j < 4; j++) {
                bf16x8 kf = *(const bf16x8*)&Ks[(j * 16 + l16) * 72 + c * 32 + quad * 8];
#pragma unroll
                for (int g = 0; g < 2; g++)
                    sc[g][j] = __builtin_amdgcn_mfma_f32_16x16x32_bf16(kf, bq_[g][c], sc[g][j], 0, 0, 0);
            }
#pragma unroll
        for (int g = 0; g < 2; g++)
#pragma unroll
            for (int j = 0; j < 4; j++) {
                bf16x4 pb = {(bf16)__builtin_amdgcn_exp2f(sc[g][j][0]),
                             (bf16)__builtin_amdgcn_exp2f(sc[g][j][1]),
                             (bf16)__builtin_amdgcn_exp2f(sc[g][j][2]),
                             (bf16)__builtin_amdgcn_exp2f(sc[g][j][3])};
                *(bf16x4*)&myP[(g * 16 + l16) * 72 + j * 16 + quad * 4] = pb;
            }
#pragma unroll
        for (int c = 0; c < 2; c++) {
            bf16x8 pf[2];
#pragma unroll
            for (int g = 0; g < 2; g++) {
                pf[g] = *(const bf16x8*)&myP[(g * 16 + l16) * 72 + c * 32 + quad * 8];
                lacc[g] = __builtin_amdgcn_mfma_f32_16x16x32_bf16(ones, pf[g], lacc[g], 0, 0, 0);
            }
#pragma unroll
            for (int t = 0; t < 4; t++) {
                bf16x8 vf = *(const bf16x8*)&Vs[(t * 16 + l16) * 72 + c * 32 + quad * 8];
#pragma unroll
                for (int g = 0; g < 2; g++)
                    ov[g][t] = __builtin_amdgcn_mfma_f32_16x16x32_bf16(vf, pf[g], ov[g][t], 0, 0, 0);
            }
        }
    }
    int b = bh >> 4, hh = bh & 15;
#pragma unroll
    for (int g = 0; g < 2; g++) {
        float inv = 1.0f / lacc[g][0];
        size_t rowb = ((size_t)(b * SEQ + q0 + wave * 32 + g * 16 + l16)) * D_MODEL + hh * 64;
#pragma unroll
        for (int t = 0; t < 4; t++) {
            bf16x4 ob = {(bf16)(ov[g][t][0] * inv), (bf16)(ov[g][t][1] * inv),
                         (bf16)(ov[g][t][2] * inv), (bf16)(ov[g][t][3] * inv)};
            *(bf16x4*)&ctx[rowb + t * 16 + quad * 4] = ob;
        }
    }
}

// ---------------------------------------------------------------------------
// Kernel 4: output projection (unchanged this round).
// ---------------------------------------------------------------------------
__global__ __launch_bounds__(256) void out_gemm(const bf16* __restrict__ ctx,
                                                const bf16* __restrict__ wot,
                                                const float* __restrict__ bo,
                                                float* __restrict__ out) {
    __shared__ bf16 As[64 * 32];
    __shared__ bf16 Bs[128 * 32];
    const int tid = threadIdx.x;
    const int lane = tid & 63, wave = tid >> 6;
    const int quad = lane >> 4, l16 = lane & 15;
    const int srow = lane >> 2, selem = (lane & 3) * 8;
    int row0 = blockIdx.y * 64, col0 = blockIdx.x * 128;
    f32x4 acc[4][2] = {};

    for (int k0 = 0; k0 < D_MODEL; k0 += 32) {
        __syncthreads();
        {
            const bf16* ga = ctx + (size_t)(row0 + wave * 16 + srow) * D_MODEL + k0 + selem;
            __builtin_amdgcn_global_load_lds((gbl_void*)ga, (lds_void*)(As + wave * 512 + lane * 8), 16, 0, 0);
        }
#pragma unroll
        for (int t = 0; t < 2; t++) {
            int m = wave * 2 + t;
            const bf16* gb = wot + (size_t)(col0 + m * 16 + srow) * D_MODEL + k0 + selem;
            __builtin_amdgcn_global_load_lds((gbl_void*)gb, (lds_void*)(Bs + m * 512 + lane * 8), 16, 0, 0);
        }
        __syncthreads();
        bf16x8 af[4], bfr[2];
#pragma unroll
        for (int i = 0; i < 4; i++)
            af[i] = *(const bf16x8*)&As[(i * 16 + l16) * 32 + quad * 8];
#pragma unroll
        for (int j = 0; j < 2; j++)
            bfr[j] = *(const bf16x8*)&Bs[(wave * 32 + j * 16 + l16) * 32 + quad * 8];
#pragma unroll
        for (int i = 0; i < 4; i++)
#pragma unroll
            for (int j = 0; j < 2; j++)
                acc[i][j] = __builtin_amdgcn_mfma_f32_16x16x32_bf16(af[i], bfr[j], acc[i][j], 0, 0, 0);
    }
#pragma unroll
    for (int i = 0; i < 4; i++)
#pragma unroll
        for (int j = 0; j < 2; j++) {
            int colg = col0 + wave * 32 + j * 16 + l16;
            float bi = bo[colg];
            int rbase = row0 + i * 16 + quad * 4;
#pragma unroll
            for (int r = 0; r < 4; r++)
                out[(size_t)(rbase + r) * D_MODEL + colg] = acc[i][j][r] + bi;
        }
}

// ---------------------------------------------------------------------------
extern "C" void kernel_launch(void* const* d_in, const int* in_sizes, int n_in,
                              void* d_out, int out_size, void* d_ws, size_t ws_size,
                              hipStream_t stream) {
    const float* x  = (const float*)d_in[0];
    const float* wq = (const float*)d_in[1];
    const float* bq = (const float*)d_in[2];
    const float* wk = (const float*)d_in[3];
    const float* bk = (const float*)d_in[4];
    const float* wv = (const float*)d_in[5];
    const float* bv = (const float*)d_in[6];
    const float* wo = (const float*)d_in[7];
    const float* bo = (const float*)d_in[8];
    float* out = (float*)d_out;

    const size_t MB = 1024 * 1024;
    char* ws = (char*)d_ws;
    bf16* xb  = (bf16*)(ws);             // [4096][1024]            8 MB
    bf16* wtb = (bf16*)(ws + 8 * MB);    // [4][1024][1024] (N,K)   8 MB
    bf16* qb  = (bf16*)(ws + 16 * MB);   // [B,H,S,64] (scaled)     8 MB
    bf16* kb  = (bf16*)(ws + 24 * MB);   // [B,H,S,64]              8 MB
    bf16* vb  = (bf16*)(ws + 32 * MB);   // [B,H,64,S]              8 MB
    bf16* ctx = (bf16*)(ws + 40 * MB);   // [4096][1024]            8 MB

    prep<<<dim3(32, 32, 8), dim3(32, 8), 0, stream>>>(wq, wk, wv, wo, x, wtb, xb);
    qkv_gemm<<<dim3(192), dim3(512), 0, stream>>>(xb, wtb, bq, bk, bv, qb, kb, vb);
    attn<<<dim3(BATCH * NHEAD, SEQ / 128), 256, 0, stream>>>(qb, kb, vb, ctx);
    out_gemm<<<dim3(8, 64), 256, 0, stream>>>(ctx, wtb + 3 * (size_t)D_MODEL * D_MODEL, bo, out);
}